// Round 9
// baseline (148.671 us; speedup 1.0000x reference)
//
#include <hip/hip_runtime.h>

typedef unsigned short ushort;
typedef __attribute__((ext_vector_type(4)))  float  f32x4;
typedef __attribute__((ext_vector_type(16))) float  f32x16;
typedef __attribute__((ext_vector_type(8)))  short  s16x8;
typedef __attribute__((ext_vector_type(4)))  ushort u16x4;
typedef __attribute__((ext_vector_type(4)))  unsigned u32x4;

#define MFMA16(a, b, c) __builtin_amdgcn_mfma_f32_16x16x32_bf16((a), (b), (c), 0, 0, 0)
#define MFMA32(a, b, c) __builtin_amdgcn_mfma_f32_32x32x16_bf16((a), (b), (c), 0, 0, 0)

__device__ __forceinline__ ushort f2bf(float f) {
    unsigned u = __builtin_bit_cast(unsigned, f);
    u = (u + 0x7FFF + ((u >> 16) & 1)) >> 16;   // RNE
    return (ushort)u;
}

__device__ __forceinline__ unsigned cvtpk_bf16(float lo, float hi) {
    unsigned r;
    asm("v_cvt_pk_bf16_f32 %0, %1, %2" : "=v"(r) : "v"(lo), "v"(hi));
    return r;
}
// After the swap: a = [a_lo31 | b_lo31], b = [a_hi31 | b_hi31].
// Only safe when a and b are DISTINCT SSA values (regalloc coalescing hazard).
__device__ __forceinline__ void plswap(unsigned& a, unsigned& b) {
    asm volatile("v_permlane32_swap_b32 %0, %1" : "+v"(a), "+v"(b));
}
__device__ __forceinline__ float pairmax(float x) {
    return fmaxf(x, __shfl_xor(x, 32));
}
__device__ __forceinline__ float pairsum(float x) {
    return x + __shfl_xor(x, 32);
}
// Raw 2^x. exp() folded to exp2 via Q pre-scale by log2(e).
__device__ __forceinline__ float fast_exp2(float x) {
    float r;
    asm("v_exp_f32 %0, %1" : "=v"(r) : "v"(x));
    return r;
}

__device__ __forceinline__ void gload_lds16(const ushort* g, ushort* l) {
    __builtin_amdgcn_global_load_lds(
        (const __attribute__((address_space(1))) void*)g,
        (__attribute__((address_space(3))) void*)l, 16, 0, 0);
}

// ---------------------------------------------------------------------------
// fp32 -> bf16 conversion for all three inputs in ONE dispatch; outputs are
// contiguous in workspace (xb | wqb | wpb).
// ---------------------------------------------------------------------------
__global__ __launch_bounds__(256) void cvt_all(
    const float* __restrict__ x, const float* __restrict__ wq,
    const float* __restrict__ wp, ushort* __restrict__ out,
    int n4x, int n4q, int n4p)
{
    int i = blockIdx.x * blockDim.x + threadIdx.x;
    const int stride = gridDim.x * blockDim.x;
    const int total = n4x + n4q + n4p;
    for (; i < total; i += stride) {
        float4 v;
        if (i < n4x)            v = ((const float4*)x)[i];
        else if (i < n4x + n4q) v = ((const float4*)wq)[i - n4x];
        else                    v = ((const float4*)wp)[i - n4x - n4q];
        u16x4 o;
        o[0] = f2bf(v.x); o[1] = f2bf(v.y); o[2] = f2bf(v.z); o[3] = f2bf(v.w);
        ((u16x4*)out)[i] = o;
    }
}

// ---------------------------------------------------------------------------
// 128x256 tile GEMM mainloop, 3-buffer / 2-deep prefetch / counted vmcnt:
// at iteration it: stage tile it+2 (6 gload_lds) into buf (it+2)%3, compute
// buf it%3 (12 ds_read_b128 + 32 MFMA per wave), then `s_waitcnt vmcnt(6)`
// + s_barrier (newest stage's loads stay in flight across the barrier).
// LDS bank swizzle: phys 16B-slot = logical ^ ((row>>1)&3), applied on the
// pre-swizzled GLOBAL source (gload_lds writes linearly) and on the read.
// LDS: A 3x8KB + B 3x16KB = 72KB. 4 waves 2x2, per-wave 64x128 (acc[4][8]).
// Requires K % 96 == 0 (nt divisible by 3); K = 768.
// ---------------------------------------------------------------------------
__device__ __forceinline__ void gemm_mainloop(
    const ushort* __restrict__ A, const ushort* __restrict__ B, int K,
    int row0, int col0, ushort* As, ushort* Bs, f32x4 acc[4][8])
{
    const int t  = threadIdx.x;
    const int l  = t & 63;
    const int w  = t >> 6;
    const int lr = l & 15, lg = l >> 4;
    const int wm = w >> 1, wn = w & 1;

#pragma unroll
    for (int m = 0; m < 4; m++)
#pragma unroll
        for (int n = 0; n < 8; n++) acc[m][n] = (f32x4){0.f, 0.f, 0.f, 0.f};

    // pre-swizzled source slot: thread t fills LDS row t>>2, phys slot t&3;
    // source slot = (t&3) ^ ((row>>1)&3) = (t&3) ^ ((t>>3)&3); +64-row
    // instruction offsets preserve the swizzle (64>>1 = 32 == 0 mod 4).
    const int slot = (t & 3) ^ ((t >> 3) & 3);
    const ushort* ga0 = A + (row0 + (t >> 2)) * K + slot * 8;
    const ushort* gb0 = B + (col0 + (t >> 2)) * K + slot * 8;
    const int rowsz = 64 * K;
    ushort* la0 = As + t * 8;
    ushort* lb0 = Bs + t * 8;

    auto STAGE = [&](int kt, int buf) {
        const int k0 = kt * 32;
        ushort* la = la0 + buf * 4096;
        ushort* lb = lb0 + buf * 8192;
        gload_lds16(ga0 + k0,             la);
        gload_lds16(ga0 + rowsz + k0,     la + 2048);
        gload_lds16(gb0 + k0,             lb);
        gload_lds16(gb0 + rowsz + k0,     lb + 2048);
        gload_lds16(gb0 + 2 * rowsz + k0, lb + 4096);
        gload_lds16(gb0 + 3 * rowsz + k0, lb + 6144);
    };
    const int sx = (lg ^ ((lr >> 1) & 3)) * 8;   // read-side swizzled slot
    auto COMPUTE = [&](int buf) {
        const ushort* Ab = As + buf * 4096;
        const ushort* Bb = Bs + buf * 8192;
        s16x8 af[4], bf[8];
#pragma unroll
        for (int m = 0; m < 4; m++)
            af[m] = *(const s16x8*)&Ab[(wm * 64 + m * 16 + lr) * 32 + sx];
#pragma unroll
        for (int n = 0; n < 8; n++)
            bf[n] = *(const s16x8*)&Bb[(wn * 128 + n * 16 + lr) * 32 + sx];
        __builtin_amdgcn_s_setprio(1);
#pragma unroll
        for (int m = 0; m < 4; m++)
#pragma unroll
            for (int n = 0; n < 8; n++)
                acc[m][n] = MFMA16(af[m], bf[n], acc[m][n]);
        __builtin_amdgcn_s_setprio(0);
    };

    const int nt = K >> 5;          // 24; divisible by 3
    STAGE(0, 0);
    STAGE(1, 1);
    asm volatile("s_waitcnt vmcnt(6)" ::: "memory");   // tile0 landed
    __builtin_amdgcn_s_barrier();

#define GSTEP(IT, CBUF, SBUF)                                          \
    {                                                                  \
        const int sk = (IT) + 2;                                       \
        const bool st = sk < nt;                                       \
        if (st) STAGE(sk, SBUF);                                       \
        COMPUTE(CBUF);                                                 \
        if (st) { asm volatile("s_waitcnt vmcnt(6)" ::: "memory"); }   \
        else    { asm volatile("s_waitcnt vmcnt(0)" ::: "memory"); }   \
        __builtin_amdgcn_s_barrier();                                  \
    }

    for (int base = 0; base < nt; base += 3) {
        GSTEP(base,     0, 2);
        GSTEP(base + 1, 1, 0);
        GSTEP(base + 2, 2, 1);
    }
#undef GSTEP
}

// ---------------------------------------------------------------------------
// Kernel 1: QKV = x @ qkv_w^T, scatter into q[bh][n][64] (pre-scaled by
// SCALE*log2e so softmax uses exp2), k[bh][n][64], vT[bh][64][n].
// grid (64, 9), block 256, tile 128x256.
// ---------------------------------------------------------------------------
__global__ __launch_bounds__(256, 2) void qkv_gemm(
    const ushort* __restrict__ X, const ushort* __restrict__ W,
    ushort* __restrict__ qb, ushort* __restrict__ kb, ushort* __restrict__ vb)
{
    __shared__ __align__(16) ushort As[3 * 128 * 32];
    __shared__ __align__(16) ushort Bs[3 * 256 * 32];
    f32x4 acc[4][8];
    const int br = blockIdx.x, bc = blockIdx.y;
    gemm_mainloop(X, W, 768, br * 128, bc * 256, As, Bs, acc);

    const int t = threadIdx.x, l = t & 63, w = t >> 6;
    const int lr = l & 15, lg = l >> 4, wm = w >> 1, wn = w & 1;
    const int p = (bc * 256) / 768;             // 768 % 256 == 0: uniform
    const int mrow0 = br * 128 + wm * 64 + lg * 4;
    const int ecolB = bc * 256 + wn * 128 + lr;
    const float QSCALE = 0.125f * 1.44269504088896f;  // SCALE * log2(e)

#pragma unroll
    for (int n = 0; n < 8; n++) {
        const int e   = ecolB + n * 16;
        const int rem = e - p * 768;
        const int h   = rem >> 6;
        const int hd  = rem & 63;
#pragma unroll
        for (int m = 0; m < 4; m++) {
            const int mr = mrow0 + m * 16;
            const int b  = mr >> 10;
            const int nn = mr & 1023;
            const f32x4 v = acc[m][n];
            const int bh = b * 12 + h;
            if (p == 0) {
                ushort* dst = qb + (bh * 1024 + nn) * 64 + hd;
#pragma unroll
                for (int r = 0; r < 4; r++) dst[r * 64] = f2bf(v[r] * QSCALE);
            } else if (p == 1) {
                ushort* dst = kb + (bh * 1024 + nn) * 64 + hd;
#pragma unroll
                for (int r = 0; r < 4; r++) dst[r * 64] = f2bf(v[r]);
            } else {
                u16x4 pk;
                pk[0] = f2bf(v[0]); pk[1] = f2bf(v[1]);
                pk[2] = f2bf(v[2]); pk[3] = f2bf(v[3]);
                *(u16x4*)(vb + (bh * 64 + hd) * 1024 + nn) = pk;
            }
        }
    }
}

// ---------------------------------------------------------------------------
// Kernel 2: flash attention, 32x32 swapped-QK, KVBLK=32 (unchanged from R8).
// grid (96 bh, 8 qt); K/V staged in LDS (coalesced gload_lds, double-buffered,
// source-side XOR swizzle), block-shared; softmax fully in-register.
// ---------------------------------------------------------------------------
__global__ __launch_bounds__(256) void attn_kernel(
    const ushort* __restrict__ qb, const ushort* __restrict__ kb,
    const ushort* __restrict__ vb, ushort* __restrict__ ao)
{
    __shared__ __align__(16) ushort KV[2][4096];   // [buf][K 2048 | V 2048] = 16KB
    const int bh = blockIdx.x, qt = blockIdx.y;
    const int b = bh / 12, h = bh - b * 12;
    const int t = threadIdx.x, l = t & 63, w = t >> 6;
    const int lq = l & 31, hi = l >> 5;
    const int qr0 = qt * 128 + w * 32;

    // ---- staging source addresses (pre-swizzled) ----
    const int l3 = l >> 3, l7 = l & 7;
    const int ku = w * 8 + l3;                      // LDS row this lane fills
    const int pfv = l7 ^ l3;                        // swizzled 16B slot index
    const char* ksrc = (const char*)kb + (size_t)(bh * 1024 + ku) * 128
                     + ((l7 ^ l3) << 4);            // + kv0*128 per iter
    const char* vsrc = (const char*)vb + (size_t)(bh * 64 + ku + 32 * ((pfv >> 2) & 1)) * 2048
                     + ((pfv & 3) << 4);            // + kv0*2 per iter
    ushort* kdst = &KV[0][0]    + w * 512 + l * 8;  // uniform base + lane*16B
    ushort* vdst = &KV[0][2048] + w * 512 + l * 8;

    // ---- Q fragments (B-operand): col=q=lq, k=d-slice s*16 + hi*8 ----
    const ushort* qlane = qb + (bh * 1024 + qr0 + lq) * 64 + hi * 8;
    s16x8 qf[4];
#pragma unroll
    for (int s = 0; s < 4; s++) qf[s] = *(const s16x8*)(qlane + s * 16);

    float m = -__builtin_inff();
    float lsum = 0.f;
    f32x16 o0 = {}, o1 = {};

    // prologue: stage tile 0 into buf 0
    gload_lds16((const ushort*)ksrc, kdst);
    gload_lds16((const ushort*)vsrc, vdst);
    __syncthreads();

    const int fx = (lq & 7) << 4;                   // read-side swizzle
    for (int it = 0; it < 32; ++it) {
        const int cur = it & 1;
        // ---- prefetch next tile into the other buffer ----
        if (it < 31) {
            const int kvn = (it + 1) * 32;
            gload_lds16((const ushort*)(ksrc + kvn * 128), kdst + (cur ^ 1) * 4096);
            gload_lds16((const ushort*)(vsrc + kvn * 2),   vdst + (cur ^ 1) * 4096);
        }
        const char* Kb = (const char*)&KV[cur][0];
        const char* Vb = (const char*)&KV[cur][2048];

        // ---- K fragments (A-operand): row kv=lq, d-slice s*16+hi*8 ----
        s16x8 kf[4];
#pragma unroll
        for (int s = 0; s < 4; s++)
            kf[s] = *(const s16x8*)(Kb + lq * 128 + ((hi * 16 + s * 32) ^ fx));

        f32x16 sa = {};
        __builtin_amdgcn_s_setprio(1);
#pragma unroll
        for (int s = 0; s < 4; s++) sa = MFMA32(kf[s], qf[s], sa);
        __builtin_amdgcn_s_setprio(0);

        // ---- in-register online softmax (16 k/lane, pair lane has rest) ----
        float tm[8];
#pragma unroll
        for (int r = 0; r < 8; r++) tm[r] = fmaxf(sa[r], sa[r + 8]);
#pragma unroll
        for (int s = 4; s; s >>= 1)
#pragma unroll
            for (int r = 0; r < s; r++) tm[r] = fmaxf(tm[r], tm[r + s]);
        const float mx = pairmax(tm[0]);

        if (!__all(mx <= m + 8.f)) {          // defer-max (T13), log2 units
            const float mn = fmaxf(m, mx);
            const float fac = fast_exp2(m - mn);
            m = mn;
            lsum *= fac;
#pragma unroll
            for (int r = 0; r < 16; r++) { o0[r] *= fac; o1[r] *= fac; }
        }

        float p[16];
#pragma unroll
        for (int r = 0; r < 16; r++) p[r] = fast_exp2(sa[r] - m);
        float ts[8];
#pragma unroll
        for (int r = 0; r < 8; r++) ts[r] = p[r] + p[r + 8];
#pragma unroll
        for (int s = 4; s; s >>= 1)
#pragma unroll
            for (int r = 0; r < s; r++) ts[r] += ts[r + s];
        lsum += pairsum(ts[0]);

        // ---- pack P^T into PV B-fragments (cvt_pk + permlane32_swap) ----
        s16x8 pfr[2];
#pragma unroll
        for (int slot = 0; slot < 2; slot++) {
            const int r0 = slot * 8;
            unsigned a0 = cvtpk_bf16(p[r0 + 0], p[r0 + 1]);
            unsigned a1 = cvtpk_bf16(p[r0 + 4], p[r0 + 5]);
            plswap(a0, a1);
            unsigned b0 = cvtpk_bf16(p[r0 + 2], p[r0 + 3]);
            unsigned b1 = cvtpk_bf16(p[r0 + 6], p[r0 + 7]);
            plswap(b0, b1);
            const u32x4 u = {a0, b0, a1, b1};
            pfr[slot] = __builtin_bit_cast(s16x8, u);
        }

        // ---- V fragments + PV: O^T += V^T * P^T ----
        s16x8 vf[2][2];   // [half d0/d32][k-slot]
#pragma unroll
        for (int half = 0; half < 2; half++)
#pragma unroll
            for (int s = 0; s < 2; s++)
                vf[half][s] = *(const s16x8*)(Vb + lq * 128 + ((half * 64 + hi * 16 + s * 32) ^ fx));
        __builtin_amdgcn_s_setprio(1);
        o0 = MFMA32(vf[0][0], pfr[0], o0);
        o1 = MFMA32(vf[1][0], pfr[0], o1);
        o0 = MFMA32(vf[0][1], pfr[1], o0);
        o1 = MFMA32(vf[1][1], pfr[1], o1);
        __builtin_amdgcn_s_setprio(0);

        __syncthreads();   // drains prefetch (vmcnt) + all reads of cur buf
    }

    // ---- epilogue: out[b][q][h*64+d] = O^T[d][q] / lsum ----
    const float inv = 1.f / lsum;
    ushort* op = ao + (b * 1024 + qr0 + lq) * 768 + h * 64 + 4 * hi;
#pragma unroll
    for (int i = 0; i < 4; i++) {
        u16x4 pk0, pk1;
#pragma unroll
        for (int j = 0; j < 4; j++) {
            pk0[j] = f2bf(o0[4 * i + j] * inv);
            pk1[j] = f2bf(o1[4 * i + j] * inv);
        }
        *(u16x4*)(op + 8 * i)      = pk0;   // d = 8i+4hi + 0..3
        *(u16x4*)(op + 32 + 8 * i) = pk1;   // d = 32 + 8i+4hi + 0..3
    }
}

// ---------------------------------------------------------------------------
// Kernel 3: out = attn_out @ proj_w^T + proj_b (fp32 out). grid (64, 3),
// tile 128x256.
// ---------------------------------------------------------------------------
__global__ __launch_bounds__(256, 2) void proj_gemm(
    const ushort* __restrict__ A, const ushort* __restrict__ W,
    const float* __restrict__ bias, float* __restrict__ out)
{
    __shared__ __align__(16) ushort As[3 * 128 * 32];
    __shared__ __align__(16) ushort Bs[3 * 256 * 32];
    f32x4 acc[4][8];
    const int br = blockIdx.x, bc = blockIdx.y;
    gemm_mainloop(A, W, 768, br * 128, bc * 256, As, Bs, acc);

    const int t = threadIdx.x, l = t & 63, w = t >> 6;
    const int lr = l & 15, lg = l >> 4, wm = w >> 1, wn = w & 1;
    const int mrow0 = br * 128 + wm * 64 + lg * 4;
    const int ecolB = bc * 256 + wn * 128 + lr;

#pragma unroll
    for (int n = 0; n < 8; n++) {
        const int e = ecolB + n * 16;
        const float bv = bias[e];
#pragma unroll
        for (int m = 0; m < 4; m++) {
            const int mr = mrow0 + m * 16;
#pragma unroll
            for (int r = 0; r < 4; r++)
                out[(mr + r) * 768 + e] = acc[m][n][r] + bv;
        }
    }
}

// ---------------------------------------------------------------------------
extern "C" void kernel_launch(void* const* d_in, const int* in_sizes, int n_in,
                              void* d_out, int out_size, void* d_ws, size_t ws_size,
                              hipStream_t stream)
{
    const float* x  = (const float*)d_in[0];   // [8,1024,768] f32
    const float* wq = (const float*)d_in[1];   // [2304,768]   f32
    const float* wp = (const float*)d_in[2];   // [768,768]    f32
    const float* pb = (const float*)d_in[3];   // [768]        f32
    float* out = (float*)d_out;                // [8,1024,768] f32

    const int NX = 8 * 1024 * 768;             // 6291456
    const int NQ = 2304 * 768;                 // 1769472
    const int NP = 768 * 768;                  // 589824
    const int SEG = 8 * 12 * 1024 * 64;        // 6291456

    ushort* xb  = (ushort*)d_ws;               // x bf16; reused as ao after qkv
    ushort* wqb = xb + NX;
    ushort* wpb = wqb + NQ;
    ushort* qb  = wpb + NP;                    // q  [bh][n][64]  (pre-scaled)
    ushort* kb  = qb + SEG;                    // k  [bh][n][64]
    ushort* vb  = kb + SEG;                    // vT [bh][64][n]
    ushort* ao  = xb;                          // attn out aliases xb (dead by then)

    cvt_all<<<2048, 256, 0, stream>>>(x, wq, wp, xb, NX / 4, NQ / 4, NP / 4);

    qkv_gemm  <<<dim3(64, 9), 256, 0, stream>>>(xb, wqb, qb, kb, vb);
    attn_kernel<<<dim3(96, 8), 256, 0, stream>>>(qb, kb, vb, ao);
    proj_gemm <<<dim3(64, 3), 256, 0, stream>>>(ao, wpb, pb, out);
}

// Round 10
// 115.823 us; speedup vs baseline: 1.2836x; 1.2836x over previous
//
#include <hip/hip_runtime.h>

typedef unsigned short ushort;
typedef __attribute__((ext_vector_type(4)))  float  f32x4;
typedef __attribute__((ext_vector_type(16))) float  f32x16;
typedef __attribute__((ext_vector_type(8)))  short  s16x8;
typedef __attribute__((ext_vector_type(4)))  ushort u16x4;
typedef __attribute__((ext_vector_type(4)))  unsigned u32x4;

#define MFMA16(a, b, c) __builtin_amdgcn_mfma_f32_16x16x32_bf16((a), (b), (c), 0, 0, 0)
#define MFMA32(a, b, c) __builtin_amdgcn_mfma_f32_32x32x16_bf16((a), (b), (c), 0, 0, 0)

__device__ __forceinline__ ushort f2bf(float f) {
    unsigned u = __builtin_bit_cast(unsigned, f);
    u = (u + 0x7FFF + ((u >> 16) & 1)) >> 16;   // RNE
    return (ushort)u;
}

__device__ __forceinline__ unsigned cvtpk_bf16(float lo, float hi) {
    unsigned r;
    asm("v_cvt_pk_bf16_f32 %0, %1, %2" : "=v"(r) : "v"(lo), "v"(hi));
    return r;
}
// After the swap: a = [a_lo31 | b_lo31], b = [a_hi31 | b_hi31].
// Only safe when a and b are DISTINCT SSA values (regalloc coalescing hazard).
__device__ __forceinline__ void plswap(unsigned& a, unsigned& b) {
    asm volatile("v_permlane32_swap_b32 %0, %1" : "+v"(a), "+v"(b));
}
__device__ __forceinline__ float pairmax(float x) {
    return fmaxf(x, __shfl_xor(x, 32));
}
__device__ __forceinline__ float pairsum(float x) {
    return x + __shfl_xor(x, 32);
}
// Raw 2^x. exp() folded to exp2 via Q pre-scale by log2(e).
__device__ __forceinline__ float fast_exp2(float x) {
    float r;
    asm("v_exp_f32 %0, %1" : "=v"(r) : "v"(x));
    return r;
}

__device__ __forceinline__ void gload_lds16(const ushort* g, ushort* l) {
    __builtin_amdgcn_global_load_lds(
        (const __attribute__((address_space(1))) void*)g,
        (__attribute__((address_space(3))) void*)l, 16, 0, 0);
}

// ---------------------------------------------------------------------------
// fp32 -> bf16 conversion for all three inputs in ONE dispatch; outputs are
// contiguous in workspace (xb | wqb | wpb).
// ---------------------------------------------------------------------------
__global__ __launch_bounds__(256) void cvt_all(
    const float* __restrict__ x, const float* __restrict__ wq,
    const float* __restrict__ wp, ushort* __restrict__ out,
    int n4x, int n4q, int n4p)
{
    int i = blockIdx.x * blockDim.x + threadIdx.x;
    const int stride = gridDim.x * blockDim.x;
    const int total = n4x + n4q + n4p;
    for (; i < total; i += stride) {
        float4 v;
        if (i < n4x)            v = ((const float4*)x)[i];
        else if (i < n4x + n4q) v = ((const float4*)wq)[i - n4x];
        else                    v = ((const float4*)wp)[i - n4x - n4q];
        u16x4 o;
        o[0] = f2bf(v.x); o[1] = f2bf(v.y); o[2] = f2bf(v.z); o[3] = f2bf(v.w);
        ((u16x4*)out)[i] = o;
    }
}

// ---------------------------------------------------------------------------
// 128x128 tile GEMM mainloop, 3-buffer / 2-deep prefetch / counted vmcnt,
// with LDS bank slot-XOR swizzle (R9-verified: conflicts 3.54M -> 0):
//   - STAGE: thread t fills LDS row t>>2, phys 16B-slot t&3; global source
//     slot = (t&3) ^ ((t>>3)&3)  (pre-swizzled source, linear LDS dest).
//   - READ:  lane (lr,lg) reads logical slot lg of row ..+lr at phys slot
//     lg ^ ((lr>>1)&3).  Values per lane identical to unswizzled version.
// Schedule: at iter it stage tile it+2 into buf (it+2)%3, compute buf it%3,
// then `s_waitcnt vmcnt(4)` + s_barrier (newest stage stays in flight).
// Requires K % 96 == 0; K = 768. LDS: 2 x 3 x 8KB = 48KB -> 3 blocks/CU.
// ---------------------------------------------------------------------------
__device__ __forceinline__ void gemm128_mainloop(
    const ushort* __restrict__ A, const ushort* __restrict__ B, int K,
    int row0, int col0, ushort* As, ushort* Bs, f32x4 acc[4][4])
{
    const int t  = threadIdx.x;
    const int l  = t & 63;
    const int w  = t >> 6;
    const int lr = l & 15, lg = l >> 4;
    const int wm = w >> 1, wn = w & 1;

#pragma unroll
    for (int m = 0; m < 4; m++)
#pragma unroll
        for (int n = 0; n < 4; n++) acc[m][n] = (f32x4){0.f, 0.f, 0.f, 0.f};

    // pre-swizzled source slot (row = t>>2; +64-row offsets preserve it)
    const int slot = (t & 3) ^ ((t >> 3) & 3);
    const ushort* ga0 = A + (row0 + (t >> 2)) * K + slot * 8;
    const ushort* gb0 = B + (col0 + (t >> 2)) * K + slot * 8;
    const int rowsz = 64 * K;
    ushort* la0 = As + t * 8;
    ushort* lb0 = Bs + t * 8;

    auto STAGE = [&](int kt, int buf) {
        const int k0  = kt * 32;
        const int off = buf * 4096;
        gload_lds16(ga0 + k0,         la0 + off);
        gload_lds16(ga0 + rowsz + k0, la0 + off + 2048);
        gload_lds16(gb0 + k0,         lb0 + off);
        gload_lds16(gb0 + rowsz + k0, lb0 + off + 2048);
    };
    const int sx = (lg ^ ((lr >> 1) & 3)) * 8;   // read-side swizzled slot
    auto COMPUTE = [&](int buf) {
        const ushort* Ab = As + buf * 4096;
        const ushort* Bb = Bs + buf * 4096;
        s16x8 af[4], bfr[4];
#pragma unroll
        for (int m = 0; m < 4; m++)
            af[m] = *(const s16x8*)&Ab[(wm * 64 + m * 16 + lr) * 32 + sx];
#pragma unroll
        for (int n = 0; n < 4; n++)
            bfr[n] = *(const s16x8*)&Bb[(wn * 64 + n * 16 + lr) * 32 + sx];
        __builtin_amdgcn_s_setprio(1);
#pragma unroll
        for (int m = 0; m < 4; m++)
#pragma unroll
            for (int n = 0; n < 4; n++)
                acc[m][n] = MFMA16(af[m], bfr[n], acc[m][n]);
        __builtin_amdgcn_s_setprio(0);
    };

    const int nt = K >> 5;          // 24; must be divisible by 3
    // prologue: tiles 0,1 in flight
    STAGE(0, 0);
    STAGE(1, 1);
    asm volatile("s_waitcnt vmcnt(4)" ::: "memory");   // tile0 landed
    __builtin_amdgcn_s_barrier();

#define GSTEP(IT, CBUF, SBUF)                                          \
    {                                                                  \
        const int sk = (IT) + 2;                                       \
        const bool st = sk < nt;                                       \
        if (st) STAGE(sk, SBUF);                                       \
        COMPUTE(CBUF);                                                 \
        if (st) { asm volatile("s_waitcnt vmcnt(4)" ::: "memory"); }   \
        else    { asm volatile("s_waitcnt vmcnt(0)" ::: "memory"); }   \
        __builtin_amdgcn_s_barrier();                                  \
    }

    for (int base = 0; base < nt; base += 3) {
        GSTEP(base,     0, 2);
        GSTEP(base + 1, 1, 0);
        GSTEP(base + 2, 2, 1);
    }
#undef GSTEP
}

// ---------------------------------------------------------------------------
// Kernel 1: QKV = x @ qkv_w^T, scatter into q[bh][n][64] (pre-scaled by
// SCALE*log2e so softmax uses exp2), k[bh][n][64], vT[bh][64][n].
// grid (64, 18), block 256.
// ---------------------------------------------------------------------------
__global__ __launch_bounds__(256) void qkv_gemm(
    const ushort* __restrict__ X, const ushort* __restrict__ W,
    ushort* __restrict__ qb, ushort* __restrict__ kb, ushort* __restrict__ vb)
{
    __shared__ __align__(16) ushort As[3 * 128 * 32];
    __shared__ __align__(16) ushort Bs[3 * 128 * 32];
    f32x4 acc[4][4];
    const int br = blockIdx.x, bc = blockIdx.y;
    gemm128_mainloop(X, W, 768, br * 128, bc * 128, As, Bs, acc);

    const int t = threadIdx.x, l = t & 63, w = t >> 6;
    const int lr = l & 15, lg = l >> 4, wm = w >> 1, wn = w & 1;
    const int p = (bc * 128) / 768;
    const int mrow0 = br * 128 + wm * 64 + lg * 4;
    const int ecolB = bc * 128 + wn * 64 + lr;
    const float QSCALE = 0.125f * 1.44269504088896f;  // SCALE * log2(e)

#pragma unroll
    for (int n = 0; n < 4; n++) {
        const int e   = ecolB + n * 16;
        const int rem = e - p * 768;
        const int h   = rem >> 6;
        const int hd  = rem & 63;
#pragma unroll
        for (int m = 0; m < 4; m++) {
            const int mr = mrow0 + m * 16;
            const int b  = mr >> 10;
            const int nn = mr & 1023;
            const f32x4 v = acc[m][n];
            const int bh = b * 12 + h;
            if (p == 0) {
                ushort* dst = qb + (bh * 1024 + nn) * 64 + hd;
#pragma unroll
                for (int r = 0; r < 4; r++) dst[r * 64] = f2bf(v[r] * QSCALE);
            } else if (p == 1) {
                ushort* dst = kb + (bh * 1024 + nn) * 64 + hd;
#pragma unroll
                for (int r = 0; r < 4; r++) dst[r * 64] = f2bf(v[r]);
            } else {
                u16x4 pk;
                pk[0] = f2bf(v[0]); pk[1] = f2bf(v[1]);
                pk[2] = f2bf(v[2]); pk[3] = f2bf(v[3]);
                *(u16x4*)(vb + (bh * 64 + hd) * 1024 + nn) = pk;
            }
        }
    }
}

// ---------------------------------------------------------------------------
// Kernel 2: flash attention, 32x32 swapped-QK, KVBLK=32 (unchanged from R8).
// grid (96 bh, 8 qt); K/V staged in LDS (coalesced gload_lds, double-buffered,
// source-side XOR swizzle), block-shared; softmax fully in-register.
// ---------------------------------------------------------------------------
__global__ __launch_bounds__(256) void attn_kernel(
    const ushort* __restrict__ qb, const ushort* __restrict__ kb,
    const ushort* __restrict__ vb, ushort* __restrict__ ao)
{
    __shared__ __align__(16) ushort KV[2][4096];   // [buf][K 2048 | V 2048] = 16KB
    const int bh = blockIdx.x, qt = blockIdx.y;
    const int b = bh / 12, h = bh - b * 12;
    const int t = threadIdx.x, l = t & 63, w = t >> 6;
    const int lq = l & 31, hi = l >> 5;
    const int qr0 = qt * 128 + w * 32;

    // ---- staging source addresses (pre-swizzled) ----
    const int l3 = l >> 3, l7 = l & 7;
    const int ku = w * 8 + l3;                      // LDS row this lane fills
    const int pfv = l7 ^ l3;                        // swizzled 16B slot index
    const char* ksrc = (const char*)kb + (size_t)(bh * 1024 + ku) * 128
                     + ((l7 ^ l3) << 4);            // + kv0*128 per iter
    const char* vsrc = (const char*)vb + (size_t)(bh * 64 + ku + 32 * ((pfv >> 2) & 1)) * 2048
                     + ((pfv & 3) << 4);            // + kv0*2 per iter
    ushort* kdst = &KV[0][0]    + w * 512 + l * 8;  // uniform base + lane*16B
    ushort* vdst = &KV[0][2048] + w * 512 + l * 8;

    // ---- Q fragments (B-operand): col=q=lq, k=d-slice s*16 + hi*8 ----
    const ushort* qlane = qb + (bh * 1024 + qr0 + lq) * 64 + hi * 8;
    s16x8 qf[4];
#pragma unroll
    for (int s = 0; s < 4; s++) qf[s] = *(const s16x8*)(qlane + s * 16);

    float m = -__builtin_inff();
    float lsum = 0.f;
    f32x16 o0 = {}, o1 = {};

    // prologue: stage tile 0 into buf 0
    gload_lds16((const ushort*)ksrc, kdst);
    gload_lds16((const ushort*)vsrc, vdst);
    __syncthreads();

    const int fx = (lq & 7) << 4;                   // read-side swizzle
    for (int it = 0; it < 32; ++it) {
        const int cur = it & 1;
        // ---- prefetch next tile into the other buffer ----
        if (it < 31) {
            const int kvn = (it + 1) * 32;
            gload_lds16((const ushort*)(ksrc + kvn * 128), kdst + (cur ^ 1) * 4096);
            gload_lds16((const ushort*)(vsrc + kvn * 2),   vdst + (cur ^ 1) * 4096);
        }
        const char* Kb = (const char*)&KV[cur][0];
        const char* Vb = (const char*)&KV[cur][2048];

        // ---- K fragments (A-operand): row kv=lq, d-slice s*16+hi*8 ----
        s16x8 kf[4];
#pragma unroll
        for (int s = 0; s < 4; s++)
            kf[s] = *(const s16x8*)(Kb + lq * 128 + ((hi * 16 + s * 32) ^ fx));

        f32x16 sa = {};
        __builtin_amdgcn_s_setprio(1);
#pragma unroll
        for (int s = 0; s < 4; s++) sa = MFMA32(kf[s], qf[s], sa);
        __builtin_amdgcn_s_setprio(0);

        // ---- in-register online softmax (16 k/lane, pair lane has rest) ----
        float tm[8];
#pragma unroll
        for (int r = 0; r < 8; r++) tm[r] = fmaxf(sa[r], sa[r + 8]);
#pragma unroll
        for (int s = 4; s; s >>= 1)
#pragma unroll
            for (int r = 0; r < s; r++) tm[r] = fmaxf(tm[r], tm[r + s]);
        const float mx = pairmax(tm[0]);

        if (!__all(mx <= m + 8.f)) {          // defer-max (T13), log2 units
            const float mn = fmaxf(m, mx);
            const float fac = fast_exp2(m - mn);
            m = mn;
            lsum *= fac;
#pragma unroll
            for (int r = 0; r < 16; r++) { o0[r] *= fac; o1[r] *= fac; }
        }

        float p[16];
#pragma unroll
        for (int r = 0; r < 16; r++) p[r] = fast_exp2(sa[r] - m);
        float ts[8];
#pragma unroll
        for (int r = 0; r < 8; r++) ts[r] = p[r] + p[r + 8];
#pragma unroll
        for (int s = 4; s; s >>= 1)
#pragma unroll
            for (int r = 0; r < s; r++) ts[r] += ts[r + s];
        lsum += pairsum(ts[0]);

        // ---- pack P^T into PV B-fragments (cvt_pk + permlane32_swap) ----
        s16x8 pfr[2];
#pragma unroll
        for (int slot = 0; slot < 2; slot++) {
            const int r0 = slot * 8;
            unsigned a0 = cvtpk_bf16(p[r0 + 0], p[r0 + 1]);
            unsigned a1 = cvtpk_bf16(p[r0 + 4], p[r0 + 5]);
            plswap(a0, a1);
            unsigned b0 = cvtpk_bf16(p[r0 + 2], p[r0 + 3]);
            unsigned b1 = cvtpk_bf16(p[r0 + 6], p[r0 + 7]);
            plswap(b0, b1);
            const u32x4 u = {a0, b0, a1, b1};
            pfr[slot] = __builtin_bit_cast(s16x8, u);
        }

        // ---- V fragments + PV: O^T += V^T * P^T ----
        s16x8 vf[2][2];   // [half d0/d32][k-slot]
#pragma unroll
        for (int half = 0; half < 2; half++)
#pragma unroll
            for (int s = 0; s < 2; s++)
                vf[half][s] = *(const s16x8*)(Vb + lq * 128 + ((half * 64 + hi * 16 + s * 32) ^ fx));
        __builtin_amdgcn_s_setprio(1);
        o0 = MFMA32(vf[0][0], pfr[0], o0);
        o1 = MFMA32(vf[1][0], pfr[0], o1);
        o0 = MFMA32(vf[0][1], pfr[1], o0);
        o1 = MFMA32(vf[1][1], pfr[1], o1);
        __builtin_amdgcn_s_setprio(0);

        __syncthreads();   // drains prefetch (vmcnt) + all reads of cur buf
    }

    // ---- epilogue: out[b][q][h*64+d] = O^T[d][q] / lsum ----
    const float inv = 1.f / lsum;
    ushort* op = ao + (b * 1024 + qr0 + lq) * 768 + h * 64 + 4 * hi;
#pragma unroll
    for (int i = 0; i < 4; i++) {
        u16x4 pk0, pk1;
#pragma unroll
        for (int j = 0; j < 4; j++) {
            pk0[j] = f2bf(o0[4 * i + j] * inv);
            pk1[j] = f2bf(o1[4 * i + j] * inv);
        }
        *(u16x4*)(op + 8 * i)      = pk0;   // d = 8i+4hi + 0..3
        *(u16x4*)(op + 32 + 8 * i) = pk1;   // d = 32 + 8i+4hi + 0..3
    }
}

// ---------------------------------------------------------------------------
// Kernel 3: out = attn_out @ proj_w^T + proj_b (fp32 out). grid (64, 6).
// ---------------------------------------------------------------------------
__global__ __launch_bounds__(256) void proj_gemm(
    const ushort* __restrict__ A, const ushort* __restrict__ W,
    const float* __restrict__ bias, float* __restrict__ out)
{
    __shared__ __align__(16) ushort As[3 * 128 * 32];
    __shared__ __align__(16) ushort Bs[3 * 128 * 32];
    f32x4 acc[4][4];
    const int br = blockIdx.x, bc = blockIdx.y;
    gemm128_mainloop(A, W, 768, br * 128, bc * 128, As, Bs, acc);

    const int t = threadIdx.x, l = t & 63, w = t >> 6;
    const int lr = l & 15, lg = l >> 4, wm = w >> 1, wn = w & 1;
    const int mrow0 = br * 128 + wm * 64 + lg * 4;
    const int ecolB = bc * 128 + wn * 64 + lr;

#pragma unroll
    for (int n = 0; n < 4; n++) {
        const int e = ecolB + n * 16;
        const float bv = bias[e];
#pragma unroll
        for (int m = 0; m < 4; m++) {
            const int mr = mrow0 + m * 16;
#pragma unroll
            for (int r = 0; r < 4; r++)
                out[(mr + r) * 768 + e] = acc[m][n][r] + bv;
        }
    }
}

// ---------------------------------------------------------------------------
extern "C" void kernel_launch(void* const* d_in, const int* in_sizes, int n_in,
                              void* d_out, int out_size, void* d_ws, size_t ws_size,
                              hipStream_t stream)
{
    const float* x  = (const float*)d_in[0];   // [8,1024,768] f32
    const float* wq = (const float*)d_in[1];   // [2304,768]   f32
    const float* wp = (const float*)d_in[2];   // [768,768]    f32
    const float* pb = (const float*)d_in[3];   // [768]        f32
    float* out = (float*)d_out;                // [8,1024,768] f32

    const int NX = 8 * 1024 * 768;             // 6291456
    const int NQ = 2304 * 768;                 // 1769472
    const int NP = 768 * 768;                  // 589824
    const int SEG = 8 * 12 * 1024 * 64;        // 6291456

    ushort* xb  = (ushort*)d_ws;               // x bf16; reused as ao after qkv
    ushort* wqb = xb + NX;
    ushort* wpb = wqb + NQ;
    ushort* qb  = wpb + NP;                    // q  [bh][n][64]  (pre-scaled)
    ushort* kb  = qb + SEG;                    // k  [bh][n][64]
    ushort* vb  = kb + SEG;                    // vT [bh][64][n]
    ushort* ao  = xb;                          // attn out aliases xb (dead by then)

    cvt_all<<<2048, 256, 0, stream>>>(x, wq, wp, xb, NX / 4, NQ / 4, NP / 4);

    qkv_gemm  <<<dim3(64, 18), 256, 0, stream>>>(xb, wqb, qb, kb, vb);
    attn_kernel<<<dim3(96, 8), 256, 0, stream>>>(qb, kb, vb, ao);
    proj_gemm <<<dim3(64, 6), 256, 0, stream>>>(ao, wpb, pb, out);
}

// Round 11
// 115.224 us; speedup vs baseline: 1.2903x; 1.0052x over previous
//
#include <hip/hip_runtime.h>

typedef unsigned short ushort;
typedef __attribute__((ext_vector_type(4)))  float  f32x4;
typedef __attribute__((ext_vector_type(16))) float  f32x16;
typedef __attribute__((ext_vector_type(8)))  short  s16x8;
typedef __attribute__((ext_vector_type(4)))  ushort u16x4;
typedef __attribute__((ext_vector_type(4)))  unsigned u32x4;

#define MFMA16(a, b, c) __builtin_amdgcn_mfma_f32_16x16x32_bf16((a), (b), (c), 0, 0, 0)
#define MFMA32(a, b, c) __builtin_amdgcn_mfma_f32_32x32x16_bf16((a), (b), (c), 0, 0, 0)

__device__ __forceinline__ ushort f2bf(float f) {
    unsigned u = __builtin_bit_cast(unsigned, f);
    u = (u + 0x7FFF + ((u >> 16) & 1)) >> 16;   // RNE
    return (ushort)u;
}

__device__ __forceinline__ unsigned cvtpk_bf16(float lo, float hi) {
    unsigned r;
    asm("v_cvt_pk_bf16_f32 %0, %1, %2" : "=v"(r) : "v"(lo), "v"(hi));
    return r;
}
// After the swap: a = [a_lo31 | b_lo31], b = [a_hi31 | b_hi31].
// Only safe when a and b are DISTINCT SSA values (regalloc coalescing hazard).
__device__ __forceinline__ void plswap(unsigned& a, unsigned& b) {
    asm volatile("v_permlane32_swap_b32 %0, %1" : "+v"(a), "+v"(b));
}
// Pair (lane ^ 32) reductions via permlane32_swap (pure VALU — the
// ds_bpermute-backed __shfl_xor(x,32) costs ~16cyc and counts LDS bank
// conflicts). The v_mov through asm forces b into a distinct physreg so
// the two tied operands of the swap cannot be coalesced (R3 hazard).
__device__ __forceinline__ float pairmax(float x) {
    unsigned a = __builtin_bit_cast(unsigned, x), b;
    asm("v_mov_b32 %0, %1" : "=v"(b) : "v"(a));
    plswap(a, b);   // a = own-half dup, b = pair-half dup (per-lane: {own,pair})
    return fmaxf(__builtin_bit_cast(float, a), __builtin_bit_cast(float, b));
}
__device__ __forceinline__ float pairsum(float x) {
    unsigned a = __builtin_bit_cast(unsigned, x), b;
    asm("v_mov_b32 %0, %1" : "=v"(b) : "v"(a));
    plswap(a, b);
    return __builtin_bit_cast(float, a) + __builtin_bit_cast(float, b);
}
// Raw 2^x. exp() folded to exp2 via Q pre-scale by log2(e).
__device__ __forceinline__ float fast_exp2(float x) {
    float r;
    asm("v_exp_f32 %0, %1" : "=v"(r) : "v"(x));
    return r;
}

__device__ __forceinline__ void gload_lds16(const ushort* g, ushort* l) {
    __builtin_amdgcn_global_load_lds(
        (const __attribute__((address_space(1))) void*)g,
        (__attribute__((address_space(3))) void*)l, 16, 0, 0);
}

// ---------------------------------------------------------------------------
// fp32 -> bf16 conversion for all three inputs in ONE dispatch; outputs are
// contiguous in workspace (xb | wqb | wpb).
// ---------------------------------------------------------------------------
__global__ __launch_bounds__(256) void cvt_all(
    const float* __restrict__ x, const float* __restrict__ wq,
    const float* __restrict__ wp, ushort* __restrict__ out,
    int n4x, int n4q, int n4p)
{
    int i = blockIdx.x * blockDim.x + threadIdx.x;
    const int stride = gridDim.x * blockDim.x;
    const int total = n4x + n4q + n4p;
    for (; i < total; i += stride) {
        float4 v;
        if (i < n4x)            v = ((const float4*)x)[i];
        else if (i < n4x + n4q) v = ((const float4*)wq)[i - n4x];
        else                    v = ((const float4*)wp)[i - n4x - n4q];
        u16x4 o;
        o[0] = f2bf(v.x); o[1] = f2bf(v.y); o[2] = f2bf(v.z); o[3] = f2bf(v.w);
        ((u16x4*)out)[i] = o;
    }
}

// ---------------------------------------------------------------------------
// 128x128 tile GEMM mainloop, 3-buffer / 2-deep prefetch / counted vmcnt,
// slot-XOR bank swizzle (conflicts measured 0). Unchanged from R10.
// ---------------------------------------------------------------------------
__device__ __forceinline__ void gemm128_mainloop(
    const ushort* __restrict__ A, const ushort* __restrict__ B, int K,
    int row0, int col0, ushort* As, ushort* Bs, f32x4 acc[4][4])
{
    const int t  = threadIdx.x;
    const int l  = t & 63;
    const int w  = t >> 6;
    const int lr = l & 15, lg = l >> 4;
    const int wm = w >> 1, wn = w & 1;

#pragma unroll
    for (int m = 0; m < 4; m++)
#pragma unroll
        for (int n = 0; n < 4; n++) acc[m][n] = (f32x4){0.f, 0.f, 0.f, 0.f};

    // pre-swizzled source slot (row = t>>2; +64-row offsets preserve it)
    const int slot = (t & 3) ^ ((t >> 3) & 3);
    const ushort* ga0 = A + (row0 + (t >> 2)) * K + slot * 8;
    const ushort* gb0 = B + (col0 + (t >> 2)) * K + slot * 8;
    const int rowsz = 64 * K;
    ushort* la0 = As + t * 8;
    ushort* lb0 = Bs + t * 8;

    auto STAGE = [&](int kt, int buf) {
        const int k0  = kt * 32;
        const int off = buf * 4096;
        gload_lds16(ga0 + k0,         la0 + off);
        gload_lds16(ga0 + rowsz + k0, la0 + off + 2048);
        gload_lds16(gb0 + k0,         lb0 + off);
        gload_lds16(gb0 + rowsz + k0, lb0 + off + 2048);
    };
    const int sx = (lg ^ ((lr >> 1) & 3)) * 8;   // read-side swizzled slot
    auto COMPUTE = [&](int buf) {
        const ushort* Ab = As + buf * 4096;
        const ushort* Bb = Bs + buf * 4096;
        s16x8 af[4], bfr[4];
#pragma unroll
        for (int m = 0; m < 4; m++)
            af[m] = *(const s16x8*)&Ab[(wm * 64 + m * 16 + lr) * 32 + sx];
#pragma unroll
        for (int n = 0; n < 4; n++)
            bfr[n] = *(const s16x8*)&Bb[(wn * 64 + n * 16 + lr) * 32 + sx];
        __builtin_amdgcn_s_setprio(1);
#pragma unroll
        for (int m = 0; m < 4; m++)
#pragma unroll
            for (int n = 0; n < 4; n++)
                acc[m][n] = MFMA16(af[m], bfr[n], acc[m][n]);
        __builtin_amdgcn_s_setprio(0);
    };

    const int nt = K >> 5;          // 24; must be divisible by 3
    STAGE(0, 0);
    STAGE(1, 1);
    asm volatile("s_waitcnt vmcnt(4)" ::: "memory");   // tile0 landed
    __builtin_amdgcn_s_barrier();

#define GSTEP(IT, CBUF, SBUF)                                          \
    {                                                                  \
        const int sk = (IT) + 2;                                       \
        const bool st = sk < nt;                                       \
        if (st) STAGE(sk, SBUF);                                       \
        COMPUTE(CBUF);                                                 \
        if (st) { asm volatile("s_waitcnt vmcnt(4)" ::: "memory"); }   \
        else    { asm volatile("s_waitcnt vmcnt(0)" ::: "memory"); }   \
        __builtin_amdgcn_s_barrier();                                  \
    }

    for (int base = 0; base < nt; base += 3) {
        GSTEP(base,     0, 2);
        GSTEP(base + 1, 1, 0);
        GSTEP(base + 2, 2, 1);
    }
#undef GSTEP
}

// ---------------------------------------------------------------------------
// Kernel 1: QKV = x @ qkv_w^T, scatter into q[bh][n][64] (pre-scaled by
// SCALE*log2e so softmax uses exp2), k[bh][n][64], vT[bh][64][n].
// grid (64, 18), block 256.
// ---------------------------------------------------------------------------
__global__ __launch_bounds__(256) void qkv_gemm(
    const ushort* __restrict__ X, const ushort* __restrict__ W,
    ushort* __restrict__ qb, ushort* __restrict__ kb, ushort* __restrict__ vb)
{
    __shared__ __align__(16) ushort As[3 * 128 * 32];
    __shared__ __align__(16) ushort Bs[3 * 128 * 32];
    f32x4 acc[4][4];
    const int br = blockIdx.x, bc = blockIdx.y;
    gemm128_mainloop(X, W, 768, br * 128, bc * 128, As, Bs, acc);

    const int t = threadIdx.x, l = t & 63, w = t >> 6;
    const int lr = l & 15, lg = l >> 4, wm = w >> 1, wn = w & 1;
    const int p = (bc * 128) / 768;
    const int mrow0 = br * 128 + wm * 64 + lg * 4;
    const int ecolB = bc * 128 + wn * 64 + lr;
    const float QSCALE = 0.125f * 1.44269504088896f;  // SCALE * log2(e)

#pragma unroll
    for (int n = 0; n < 4; n++) {
        const int e   = ecolB + n * 16;
        const int rem = e - p * 768;
        const int h   = rem >> 6;
        const int hd  = rem & 63;
#pragma unroll
        for (int m = 0; m < 4; m++) {
            const int mr = mrow0 + m * 16;
            const int b  = mr >> 10;
            const int nn = mr & 1023;
            const f32x4 v = acc[m][n];
            const int bh = b * 12 + h;
            if (p == 0) {
                ushort* dst = qb + (bh * 1024 + nn) * 64 + hd;
#pragma unroll
                for (int r = 0; r < 4; r++) dst[r * 64] = f2bf(v[r] * QSCALE);
            } else if (p == 1) {
                ushort* dst = kb + (bh * 1024 + nn) * 64 + hd;
#pragma unroll
                for (int r = 0; r < 4; r++) dst[r * 64] = f2bf(v[r]);
            } else {
                u16x4 pk;
                pk[0] = f2bf(v[0]); pk[1] = f2bf(v[1]);
                pk[2] = f2bf(v[2]); pk[3] = f2bf(v[3]);
                *(u16x4*)(vb + (bh * 64 + hd) * 1024 + nn) = pk;
            }
        }
    }
}

// ---------------------------------------------------------------------------
// Kernel 2: flash attention, 32x32 swapped-QK, KVBLK=32; LDS-staged K/V
// (double-buffered, source-side XOR swizzle); softmax fully in-register;
// pair reductions via permlane32_swap (no DS ops in the softmax path).
// grid (96 bh, 8 qt): all q-tiles of one head share an XCD's L2.
// ---------------------------------------------------------------------------
__global__ __launch_bounds__(256) void attn_kernel(
    const ushort* __restrict__ qb, const ushort* __restrict__ kb,
    const ushort* __restrict__ vb, ushort* __restrict__ ao)
{
    __shared__ __align__(16) ushort KV[2][4096];   // [buf][K 2048 | V 2048] = 16KB
    const int bh = blockIdx.x, qt = blockIdx.y;
    const int b = bh / 12, h = bh - b * 12;
    const int t = threadIdx.x, l = t & 63, w = t >> 6;
    const int lq = l & 31, hi = l >> 5;
    const int qr0 = qt * 128 + w * 32;

    // ---- staging source addresses (pre-swizzled) ----
    const int l3 = l >> 3, l7 = l & 7;
    const int ku = w * 8 + l3;                      // LDS row this lane fills
    const int pfv = l7 ^ l3;                        // swizzled 16B slot index
    const char* ksrc = (const char*)kb + (size_t)(bh * 1024 + ku) * 128
                     + ((l7 ^ l3) << 4);            // + kv0*128 per iter
    const char* vsrc = (const char*)vb + (size_t)(bh * 64 + ku + 32 * ((pfv >> 2) & 1)) * 2048
                     + ((pfv & 3) << 4);            // + kv0*2 per iter
    ushort* kdst = &KV[0][0]    + w * 512 + l * 8;  // uniform base + lane*16B
    ushort* vdst = &KV[0][2048] + w * 512 + l * 8;

    // ---- Q fragments (B-operand): col=q=lq, k=d-slice s*16 + hi*8 ----
    const ushort* qlane = qb + (bh * 1024 + qr0 + lq) * 64 + hi * 8;
    s16x8 qf[4];
#pragma unroll
    for (int s = 0; s < 4; s++) qf[s] = *(const s16x8*)(qlane + s * 16);

    float m = -__builtin_inff();
    float lsum = 0.f;
    f32x16 o0 = {}, o1 = {};

    // prologue: stage tile 0 into buf 0
    gload_lds16((const ushort*)ksrc, kdst);
    gload_lds16((const ushort*)vsrc, vdst);
    __syncthreads();

    const int fx = (lq & 7) << 4;                   // read-side swizzle
    for (int it = 0; it < 32; ++it) {
        const int cur = it & 1;
        // ---- prefetch next tile into the other buffer ----
        if (it < 31) {
            const int kvn = (it + 1) * 32;
            gload_lds16((const ushort*)(ksrc + kvn * 128), kdst + (cur ^ 1) * 4096);
            gload_lds16((const ushort*)(vsrc + kvn * 2),   vdst + (cur ^ 1) * 4096);
        }
        const char* Kb = (const char*)&KV[cur][0];
        const char* Vb = (const char*)&KV[cur][2048];

        // ---- K fragments (A-operand): row kv=lq, d-slice s*16+hi*8 ----
        s16x8 kf[4];
#pragma unroll
        for (int s = 0; s < 4; s++)
            kf[s] = *(const s16x8*)(Kb + lq * 128 + ((hi * 16 + s * 32) ^ fx));

        f32x16 sa = {};
        __builtin_amdgcn_s_setprio(1);
#pragma unroll
        for (int s = 0; s < 4; s++) sa = MFMA32(kf[s], qf[s], sa);
        __builtin_amdgcn_s_setprio(0);

        // ---- in-register online softmax (16 k/lane, pair lane has rest) ----
        // max tree shaped as nested triples so clang can fuse v_max3_f32
        float g0 = fmaxf(fmaxf(sa[0],  sa[1]),  sa[2]);
        float g1 = fmaxf(fmaxf(sa[3],  sa[4]),  sa[5]);
        float g2 = fmaxf(fmaxf(sa[6],  sa[7]),  sa[8]);
        float g3 = fmaxf(fmaxf(sa[9],  sa[10]), sa[11]);
        float g4 = fmaxf(fmaxf(sa[12], sa[13]), sa[14]);
        float h0 = fmaxf(fmaxf(g0, g1), g2);
        float h1 = fmaxf(fmaxf(g3, g4), sa[15]);
        const float mx = pairmax(fmaxf(h0, h1));

        if (!__all(mx <= m + 8.f)) {          // defer-max (T13), log2 units
            const float mn = fmaxf(m, mx);
            const float fac = fast_exp2(m - mn);
            m = mn;
            lsum *= fac;
#pragma unroll
            for (int r = 0; r < 16; r++) { o0[r] *= fac; o1[r] *= fac; }
        }

        float p[16];
#pragma unroll
        for (int r = 0; r < 16; r++) p[r] = fast_exp2(sa[r] - m);
        float ts[8];
#pragma unroll
        for (int r = 0; r < 8; r++) ts[r] = p[r] + p[r + 8];
#pragma unroll
        for (int s = 4; s; s >>= 1)
#pragma unroll
            for (int r = 0; r < s; r++) ts[r] += ts[r + s];
        lsum += pairsum(ts[0]);

        // ---- pack P^T into PV B-fragments (cvt_pk + permlane32_swap) ----
        s16x8 pfr[2];
#pragma unroll
        for (int slot = 0; slot < 2; slot++) {
            const int r0 = slot * 8;
            unsigned a0 = cvtpk_bf16(p[r0 + 0], p[r0 + 1]);
            unsigned a1 = cvtpk_bf16(p[r0 + 4], p[r0 + 5]);
            plswap(a0, a1);
            unsigned b0 = cvtpk_bf16(p[r0 + 2], p[r0 + 3]);
            unsigned b1 = cvtpk_bf16(p[r0 + 6], p[r0 + 7]);
            plswap(b0, b1);
            const u32x4 u = {a0, b0, a1, b1};
            pfr[slot] = __builtin_bit_cast(s16x8, u);
        }

        // ---- V fragments + PV: O^T += V^T * P^T ----
        s16x8 vf[2][2];   // [half d0/d32][k-slot]
#pragma unroll
        for (int half = 0; half < 2; half++)
#pragma unroll
            for (int s = 0; s < 2; s++)
                vf[half][s] = *(const s16x8*)(Vb + lq * 128 + ((half * 64 + hi * 16 + s * 32) ^ fx));
        __builtin_amdgcn_s_setprio(1);
        o0 = MFMA32(vf[0][0], pfr[0], o0);
        o1 = MFMA32(vf[1][0], pfr[0], o1);
        o0 = MFMA32(vf[0][1], pfr[1], o0);
        o1 = MFMA32(vf[1][1], pfr[1], o1);
        __builtin_amdgcn_s_setprio(0);

        __syncthreads();   // drains prefetch (vmcnt) + all reads of cur buf
    }

    // ---- epilogue: out[b][q][h*64+d] = O^T[d][q] / lsum ----
    const float inv = 1.f / lsum;
    ushort* op = ao + (b * 1024 + qr0 + lq) * 768 + h * 64 + 4 * hi;
#pragma unroll
    for (int i = 0; i < 4; i++) {
        u16x4 pk0, pk1;
#pragma unroll
        for (int j = 0; j < 4; j++) {
            pk0[j] = f2bf(o0[4 * i + j] * inv);
            pk1[j] = f2bf(o1[4 * i + j] * inv);
        }
        *(u16x4*)(op + 8 * i)      = pk0;   // d = 8i+4hi + 0..3
        *(u16x4*)(op + 32 + 8 * i) = pk1;   // d = 32 + 8i+4hi + 0..3
    }
}

// ---------------------------------------------------------------------------
// Kernel 3: out = attn_out @ proj_w^T + proj_b (fp32 out). grid (64, 6).
// ---------------------------------------------------------------------------
__global__ __launch_bounds__(256) void proj_gemm(
    const ushort* __restrict__ A, const ushort* __restrict__ W,
    const float* __restrict__ bias, float* __restrict__ out)
{
    __shared__ __align__(16) ushort As[3 * 128 * 32];
    __shared__ __align__(16) ushort Bs[3 * 128 * 32];
    f32x4 acc[4][4];
    const int br = blockIdx.x, bc = blockIdx.y;
    gemm128_mainloop(A, W, 768, br * 128, bc * 128, As, Bs, acc);

    const int t = threadIdx.x, l = t & 63, w = t >> 6;
    const int lr = l & 15, lg = l >> 4, wm = w >> 1, wn = w & 1;
    const int mrow0 = br * 128 + wm * 64 + lg * 4;
    const int ecolB = bc * 128 + wn * 64 + lr;

#pragma unroll
    for (int n = 0; n < 4; n++) {
        const int e = ecolB + n * 16;
        const float bv = bias[e];
#pragma unroll
        for (int m = 0; m < 4; m++) {
            const int mr = mrow0 + m * 16;
#pragma unroll
            for (int r = 0; r < 4; r++)
                out[(mr + r) * 768 + e] = acc[m][n][r] + bv;
        }
    }
}

// ---------------------------------------------------------------------------
extern "C" void kernel_launch(void* const* d_in, const int* in_sizes, int n_in,
                              void* d_out, int out_size, void* d_ws, size_t ws_size,
                              hipStream_t stream)
{
    const float* x  = (const float*)d_in[0];   // [8,1024,768] f32
    const float* wq = (const float*)d_in[1];   // [2304,768]   f32
    const float* wp = (const float*)d_in[2];   // [768,768]    f32
    const float* pb = (const float*)d_in[3];   // [768]        f32
    float* out = (float*)d_out;                // [8,1024,768] f32

    const int NX = 8 * 1024 * 768;             // 6291456
    const int NQ = 2304 * 768;                 // 1769472
    const int NP = 768 * 768;                  // 589824
    const int SEG = 8 * 12 * 1024 * 64;        // 6291456

    ushort* xb  = (ushort*)d_ws;               // x bf16; reused as ao after qkv
    ushort* wqb = xb + NX;
    ushort* wpb = wqb + NQ;
    ushort* qb  = wpb + NP;                    // q  [bh][n][64]  (pre-scaled)
    ushort* kb  = qb + SEG;                    // k  [bh][n][64]
    ushort* vb  = kb + SEG;                    // vT [bh][64][n]
    ushort* ao  = xb;                          // attn out aliases xb (dead by then)

    cvt_all<<<2048, 256, 0, stream>>>(x, wq, wp, xb, NX / 4, NQ / 4, NP / 4);

    qkv_gemm  <<<dim3(64, 18), 256, 0, stream>>>(xb, wqb, qb, kb, vb);
    attn_kernel<<<dim3(96, 8), 256, 0, stream>>>(qb, kb, vb, ao);
    proj_gemm <<<dim3(64, 6), 256, 0, stream>>>(ao, wpb, pb, out);
}